// Round 5
// baseline (691.846 us; speedup 1.0000x reference)
//
#include <hip/hip_runtime.h>
#include <hip/hip_bf16.h>
#include <math.h>

#define NOBJ 100000
#define SMOOTH 12.0f

typedef __attribute__((ext_vector_type(8))) short bf16x8;
typedef __attribute__((ext_vector_type(4))) float f32x4;
typedef unsigned short u16;
typedef unsigned int u32;
typedef unsigned long long u64;

// bf16 weight table
#define OFF_UWI 0
#define OFF_UWO 4096
#define OFF_BWI 8192
#define OFF_BWO 24576
#define OFF_TWI 40960
#define OFF_TWO 77824
#define OFF_PWI 114688
#define OFF_PWO 131072
#define WTOT    139264
__device__ u16 g_wbf[WTOT];

__device__ __forceinline__ u16 f2b(float x) {
    union { float f; u32 u; } v; v.f = x;
    u32 r = v.u + 0x7FFFu + ((v.u >> 16) & 1);
    return (u16)(r >> 16);
}
__device__ __forceinline__ float b2f(u16 b) {
    union { u32 u; float f; } v; v.u = ((u32)b) << 16; return v.f;
}
__device__ __forceinline__ u32 enc_f32(float v) {
    int b = __float_as_int(v);
    return (b >= 0) ? ((u32)b | 0x80000000u) : ~((u32)b);
}
__device__ __forceinline__ float mish_fast(float x) {
    float e = __expf(fminf(x, 15.f));
    float t = __builtin_fmaf(e, e, 2.f * e);
    return x * t * __builtin_amdgcn_rcpf(t + 2.f);
}
__device__ __forceinline__ double exp12_f64(float m) {
    float t = m * (SMOOTH * 1.4426950408889634f);
    float n = floorf(t);
    float f = exp2f(t - n);
    return ldexp((double)f, (int)n);
}
__device__ __forceinline__ float lse_from_sum(double S) {
    if (S == 0.0) return -3.0701134573253942f;  // log(1e-16)/12
    union { double d; u64 u; } vu; vu.d = S;
    int k = (int)((vu.u >> 52) & 0x7FF) - 1022;
    vu.u = (vu.u & 0x000FFFFFFFFFFFFFULL) | 0x3FE0000000000000ULL;
    float fr = (float)vu.d;
    return ((float)k + __log2f(fr)) * 0.057762265046662105f;  // *ln2/12
}

__global__ void conv_weights(const float* __restrict__ uwi, const float* __restrict__ uwo,
                             const float* __restrict__ bwi, const float* __restrict__ bwo,
                             const float* __restrict__ twi, const float* __restrict__ two_,
                             const float* __restrict__ pwi, const float* __restrict__ pwo) {
    int i = blockIdx.x * 256 + threadIdx.x;
    if (i >= WTOT) return;
    const float* src; int off;
    if      (i < OFF_UWO) { src = uwi; off = OFF_UWI; }
    else if (i < OFF_BWI) { src = uwo; off = OFF_UWO; }
    else if (i < OFF_BWO) { src = bwi; off = OFF_BWI; }
    else if (i < OFF_TWI) { src = bwo; off = OFF_BWO; }
    else if (i < OFF_TWO) { src = twi; off = OFF_TWI; }
    else if (i < OFF_PWI) { src = two_; off = OFF_TWO; }
    else if (i < OFF_PWO) { src = pwi; off = OFF_PWI; }
    else                  { src = pwo; off = OFF_PWO; }
    g_wbf[i] = f2b(src[i - off]);
}

__device__ __forceinline__ int lookup_obj(long long m,
                                          const int* __restrict__ iu, int nU,
                                          const int* __restrict__ ib, int nB,
                                          const int* __restrict__ it) {
    if (m < nU) return iu[m];
    m -= nU;
    if (m < nB) return ib[m];
    return it[m - nB];
}

// ---------- CSR build ----------
__global__ void hist_kernel(const int* __restrict__ iu, int nU,
                            const int* __restrict__ ib, int nB,
                            const int* __restrict__ it, int nT,
                            u32* __restrict__ counts) {
    long long t = (long long)blockIdx.x * 256 + threadIdx.x;
    if (t >= (long long)nU + nB + nT) return;
    atomicAdd(&counts[lookup_obj(t, iu, nU, ib, nB, it)], 1u);
}

__global__ void scan1_kernel(const u32* __restrict__ counts, u32* __restrict__ offs,
                             u32* __restrict__ bsum) {
    __shared__ u32 s[256];
    int t = threadIdx.x;
    int g = blockIdx.x * 256 + t;
    u32 v = (g < NOBJ) ? counts[g] : 0u;
    s[t] = v; __syncthreads();
    for (int off = 1; off < 256; off <<= 1) {
        u32 x = (t >= off) ? s[t - off] : 0u; __syncthreads();
        s[t] += x; __syncthreads();
    }
    if (g < NOBJ) offs[g] = s[t] - v;          // exclusive
    if (t == 255) bsum[blockIdx.x] = s[255];
}

__global__ void scan2_kernel(u32* __restrict__ bsum, int nblk) {
    __shared__ u32 s[512];
    int t = threadIdx.x;
    u32 v = (t < nblk) ? bsum[t] : 0u;
    s[t] = v; __syncthreads();
    for (int off = 1; off < 512; off <<= 1) {
        u32 x = (t >= off) ? s[t - off] : 0u; __syncthreads();
        s[t] += x; __syncthreads();
    }
    if (t < nblk) bsum[t] = s[t] - v;          // exclusive
}

__global__ void scan3_kernel(u32* __restrict__ offs, const u32* __restrict__ bsum) {
    int g = blockIdx.x * 256 + threadIdx.x;
    if (g < NOBJ) offs[g] += bsum[blockIdx.x];
}

__global__ void fill_kernel(const int* __restrict__ iu, int nU,
                            const int* __restrict__ ib, int nB,
                            const int* __restrict__ it, int nT,
                            const u32* __restrict__ offs, u32* __restrict__ cursor,
                            u32* __restrict__ reflist) {
    long long t = (long long)blockIdx.x * 256 + threadIdx.x;
    if (t >= (long long)nU + nB + nT) return;
    int obj = lookup_obj(t, iu, nU, ib, nB, it);
    u32 pos = atomicAdd(&cursor[obj], 1u);
    reflist[offs[obj] + pos] = (u32)t;
}

// ---------- fused relation MLP ----------
// MODE 0: atomicMax(enc) | MODE 1: f32 expsum atomic | MODE 2: f64 expsum atomic
// MODE 3: write message rows as f16 to msgs_out (CSR path, no atomics)
template<int D, int MW, int MODE, int WOFF_I, int WOFF_O>
__global__ __launch_bounds__(64 * MW)
void rel_pass_mfma(const float* __restrict__ emb,
                   const int* __restrict__ idx, int nRows,
                   const float* __restrict__ bi, const float* __restrict__ bo,
                   u32* __restrict__ mx_enc, const float* __restrict__ mx,
                   float* __restrict__ ssum, double* __restrict__ ssum64,
                   u16* __restrict__ msgs_out, long long base64) {
    constexpr int ARITY = D / 64;
    constexpr int NT = D / 16;
    constexpr int KT = D / 32;
    constexpr int M = MW * 16;
    __shared__ u16 xs[M * D];
    __shared__ u16 hs[M * D];
    __shared__ int objsm[M * ARITY];

    const int tid = threadIdx.x;
    const int w = tid >> 6, l = tid & 63;
    const int lo = l & 15, hi = l >> 4;
    const int row0 = blockIdx.x * M;

    for (int i = tid; i < M * ARITY; i += 64 * MW) {
        int row = row0 + i / ARITY;
        objsm[i] = (row < nRows) ? idx[(size_t)row * ARITY + i % ARITY] : -1;
    }
    __syncthreads();
    for (int i = tid; i < M * D / 4; i += 64 * MW) {
        int r = i / (D / 4), c4 = i % (D / 4);
        int obj = objsm[r * ARITY + (c4 >> 4)];
        float4 v = make_float4(0.f, 0.f, 0.f, 0.f);
        if (obj >= 0) v = *(const float4*)(emb + (size_t)obj * 64 + (c4 & 15) * 4);
        int sw = (r * D + c4 * 4) ^ ((r & 7) << 3);
        ushort4 o;
        o.x = f2b(v.x); o.y = f2b(v.y); o.z = f2b(v.z); o.w = f2b(v.w);
        *(ushort4*)&xs[sw] = o;
    }
    __syncthreads();

    f32x4 acc[NT];
    const int arow = w * 16 + lo;
    const int asw = ((arow & 7) << 3);

#pragma unroll
    for (int n = 0; n < NT; ++n) { float b = bi[n * 16 + lo]; acc[n] = (f32x4){b, b, b, b}; }
#pragma unroll
    for (int kk = 0; kk < KT; ++kk) {
        bf16x8 a = *(const bf16x8*)&xs[(arow * D + kk * 32 + hi * 8) ^ asw];
#pragma unroll
        for (int n = 0; n < NT; ++n) {
            bf16x8 b = *(const bf16x8*)&g_wbf[WOFF_I + (n * 16 + lo) * D + kk * 32 + hi * 8];
            acc[n] = __builtin_amdgcn_mfma_f32_16x16x32_bf16(a, b, acc[n], 0, 0, 0);
        }
    }
#pragma unroll
    for (int n = 0; n < NT; ++n) {
#pragma unroll
        for (int r = 0; r < 4; ++r) {
            int row = w * 16 + hi * 4 + r;
            int col = n * 16 + lo;
            hs[(row * D + col) ^ ((row & 7) << 3)] = f2b(mish_fast(acc[n][r]));
        }
    }
    __syncthreads();

#pragma unroll
    for (int n = 0; n < NT; ++n) { float b = bo[n * 16 + lo]; acc[n] = (f32x4){b, b, b, b}; }
#pragma unroll
    for (int kk = 0; kk < KT; ++kk) {
        bf16x8 a = *(const bf16x8*)&hs[(arow * D + kk * 32 + hi * 8) ^ asw];
#pragma unroll
        for (int n = 0; n < NT; ++n) {
            bf16x8 b = *(const bf16x8*)&g_wbf[WOFF_O + (n * 16 + lo) * D + kk * 32 + hi * 8];
            acc[n] = __builtin_amdgcn_mfma_f32_16x16x32_bf16(a, b, acc[n], 0, 0, 0);
        }
    }

    if (MODE == 3) {
        // store msg f16 into hs (each wave touches only its own 16 rows), then coalesced dump
#pragma unroll
        for (int n = 0; n < NT; ++n) {
            int col = n * 16 + lo;
#pragma unroll
            for (int r = 0; r < 4; ++r) {
                int row = w * 16 + hi * 4 + r;
                float m = b2f(xs[(row * D + col) ^ ((row & 7) << 3)]) + acc[n][r];
                _Float16 hv = (_Float16)m;
                hs[(row * D + col) ^ ((row & 7) << 3)] = *(u16*)&hv;
            }
        }
        __syncthreads();
        u16* dst = msgs_out + base64 + (size_t)row0 * D;
        for (int i = tid; i < M * D / 8; i += 64 * MW) {
            int u = i * 8;
            int row = u / D, off = u - row * D;
            int sw2 = (row * D + off) ^ ((row & 7) << 3);
            *(bf16x8*)(dst + u) = *(const bf16x8*)&hs[sw2];
        }
    } else {
#pragma unroll
        for (int n = 0; n < NT; ++n) {
            int col = n * 16 + lo;
#pragma unroll
            for (int r = 0; r < 4; ++r) {
                int row = w * 16 + hi * 4 + r;
                int obj = objsm[row * ARITY + (col >> 6)];
                if (obj < 0) continue;
                float xv = b2f(xs[(row * D + col) ^ ((row & 7) << 3)]);
                float m = xv + acc[n][r];
                size_t dst = (size_t)obj * 64 + (col & 63);
                if (MODE == 0) atomicMax(&mx_enc[dst], enc_f32(m));
                else if (MODE == 1) atomicAdd(&ssum[dst], __expf(SMOOTH * (m - mx[dst])));
                else unsafeAtomicAdd(&ssum64[dst], exp12_f64(m));
            }
        }
    }
}

__global__ void mx_decode_kernel(u32* __restrict__ mx, long long n) {
    long long tid = (long long)blockIdx.x * blockDim.x + threadIdx.x;
    if (tid >= n) return;
    u32 u = mx[tid];
    float v;
    if (u == 0u) v = 0.0f;
    else {
        int b = (u & 0x80000000u) ? (int)(u & 0x7FFFFFFFu) : (int)(~u);
        v = __int_as_float(b);
    }
    ((float*)mx)[tid] = v;
}

// ---------- fused CSR aggregate + update MLP (no atomics) ----------
__global__ __launch_bounds__(256)
void agg_update(const float* __restrict__ emb, const u16* __restrict__ msgs,
                const u32* __restrict__ offs, const u32* __restrict__ counts,
                const u32* __restrict__ reflist,
                const float* __restrict__ bi, const float* __restrict__ bo,
                float* __restrict__ out) {
    __shared__ u16 uin[64 * 128];
    __shared__ u16 h[64 * 128];
    const int tid = threadIdx.x;
    const int w = tid >> 6, l = tid & 63, lo = l & 15, hi = l >> 4;
    const int row0 = blockIdx.x * 64;

    // wave w aggregates objects row0 + w*16 .. +15; lane l = column
    for (int rr = 0; rr < 16; ++rr) {
        int row = w * 16 + rr;
        int obj = row0 + row;
        float lse = -3.0701134573253942f, ev = 0.f;
        if (obj < NOBJ) {
            u32 off = offs[obj], n = counts[obj];
            double S = 0.0;
            for (u32 bj = 0; bj < n; bj += 64) {
                u32 rem = n - bj;
                int rl = 0;
                if (l < rem) rl = (int)reflist[off + bj + l];
                int lim = rem < 64u ? (int)rem : 64;
                for (int j = 0; j < lim; ++j) {
                    int ref = __shfl(rl, j);
                    u16 hb = msgs[(size_t)ref * 64 + l];
                    float v = (float)(*(const _Float16*)&hb);
                    S += exp12_f64(v);
                }
            }
            lse = lse_from_sum(S);
            ev = emb[(size_t)obj * 64 + l];
        }
        uin[(row * 128 + l) ^ ((row & 7) << 3)] = f2b(lse);
        uin[(row * 128 + 64 + l) ^ ((row & 7) << 3)] = f2b(ev);
    }
    __syncthreads();

    const int arow = w * 16 + lo;
    const int asw = ((arow & 7) << 3);
    f32x4 acc[8];
#pragma unroll
    for (int n = 0; n < 8; ++n) { float b = bi[n * 16 + lo]; acc[n] = (f32x4){b, b, b, b}; }
#pragma unroll
    for (int kk = 0; kk < 4; ++kk) {
        bf16x8 a = *(const bf16x8*)&uin[(arow * 128 + kk * 32 + hi * 8) ^ asw];
#pragma unroll
        for (int n = 0; n < 8; ++n) {
            bf16x8 b = *(const bf16x8*)&g_wbf[OFF_PWI + (n * 16 + lo) * 128 + kk * 32 + hi * 8];
            acc[n] = __builtin_amdgcn_mfma_f32_16x16x32_bf16(a, b, acc[n], 0, 0, 0);
        }
    }
#pragma unroll
    for (int n = 0; n < 8; ++n) {
#pragma unroll
        for (int r = 0; r < 4; ++r) {
            int row = w * 16 + hi * 4 + r;
            int col = n * 16 + lo;
            h[(row * 128 + col) ^ ((row & 7) << 3)] = f2b(mish_fast(acc[n][r]));
        }
    }
    __syncthreads();

    f32x4 acc2[4];
#pragma unroll
    for (int n = 0; n < 4; ++n) { float b = bo[n * 16 + lo]; acc2[n] = (f32x4){b, b, b, b}; }
#pragma unroll
    for (int kk = 0; kk < 4; ++kk) {
        bf16x8 a = *(const bf16x8*)&h[(arow * 128 + kk * 32 + hi * 8) ^ asw];
#pragma unroll
        for (int n = 0; n < 4; ++n) {
            bf16x8 b = *(const bf16x8*)&g_wbf[OFF_PWO + (n * 16 + lo) * 128 + kk * 32 + hi * 8];
            acc2[n] = __builtin_amdgcn_mfma_f32_16x16x32_bf16(a, b, acc2[n], 0, 0, 0);
        }
    }
#pragma unroll
    for (int n = 0; n < 4; ++n) {
        int col = n * 16 + lo;
#pragma unroll
        for (int r = 0; r < 4; ++r) {
            int row = w * 16 + hi * 4 + r;
            int obj = row0 + row;
            if (obj < NOBJ)
                out[(size_t)obj * 64 + col] = emb[(size_t)obj * 64 + col] + acc2[n][r];
        }
    }
}

// update kernel for fallback paths
template<int P64>
__global__ __launch_bounds__(256)
void update_mfma(const float* __restrict__ emb,
                 const float* __restrict__ mx, const float* __restrict__ ssum,
                 const double* __restrict__ ssum64,
                 const float* __restrict__ bi, const float* __restrict__ bo,
                 float* __restrict__ out) {
    __shared__ u16 uin[64 * 128];
    __shared__ u16 h[64 * 128];
    const int tid = threadIdx.x;
    const int w = tid >> 6, l = tid & 63, lo = l & 15, hi = l >> 4;
    const int row0 = blockIdx.x * 64;

    for (int i = tid; i < 64 * 128; i += 256) {
        int r = i >> 7, c = i & 127;
        int obj = row0 + r;
        float v = 0.f;
        if (obj < NOBJ) {
            if (c < 64) {
                if (P64) v = lse_from_sum(ssum64[(size_t)obj * 64 + c]);
                else {
                    float s = ssum[(size_t)obj * 64 + c] + 1e-16f;
                    v = __logf(s) * (1.f / SMOOTH) + mx[(size_t)obj * 64 + c];
                }
            } else v = emb[(size_t)obj * 64 + (c - 64)];
        }
        uin[i ^ ((r & 7) << 3)] = f2b(v);
    }
    __syncthreads();

    const int arow = w * 16 + lo;
    const int asw = ((arow & 7) << 3);
    f32x4 acc[8];
#pragma unroll
    for (int n = 0; n < 8; ++n) { float b = bi[n * 16 + lo]; acc[n] = (f32x4){b, b, b, b}; }
#pragma unroll
    for (int kk = 0; kk < 4; ++kk) {
        bf16x8 a = *(const bf16x8*)&uin[(arow * 128 + kk * 32 + hi * 8) ^ asw];
#pragma unroll
        for (int n = 0; n < 8; ++n) {
            bf16x8 b = *(const bf16x8*)&g_wbf[OFF_PWI + (n * 16 + lo) * 128 + kk * 32 + hi * 8];
            acc[n] = __builtin_amdgcn_mfma_f32_16x16x32_bf16(a, b, acc[n], 0, 0, 0);
        }
    }
#pragma unroll
    for (int n = 0; n < 8; ++n) {
#pragma unroll
        for (int r = 0; r < 4; ++r) {
            int row = w * 16 + hi * 4 + r;
            int col = n * 16 + lo;
            h[(row * 128 + col) ^ ((row & 7) << 3)] = f2b(mish_fast(acc[n][r]));
        }
    }
    __syncthreads();
    f32x4 acc2[4];
#pragma unroll
    for (int n = 0; n < 4; ++n) { float b = bo[n * 16 + lo]; acc2[n] = (f32x4){b, b, b, b}; }
#pragma unroll
    for (int kk = 0; kk < 4; ++kk) {
        bf16x8 a = *(const bf16x8*)&h[(arow * 128 + kk * 32 + hi * 8) ^ asw];
#pragma unroll
        for (int n = 0; n < 4; ++n) {
            bf16x8 b = *(const bf16x8*)&g_wbf[OFF_PWO + (n * 16 + lo) * 128 + kk * 32 + hi * 8];
            acc2[n] = __builtin_amdgcn_mfma_f32_16x16x32_bf16(a, b, acc2[n], 0, 0, 0);
        }
    }
#pragma unroll
    for (int n = 0; n < 4; ++n) {
        int col = n * 16 + lo;
#pragma unroll
        for (int r = 0; r < 4; ++r) {
            int row = w * 16 + hi * 4 + r;
            int obj = row0 + row;
            if (obj < NOBJ)
                out[(size_t)obj * 64 + col] = emb[(size_t)obj * 64 + col] + acc2[n][r];
        }
    }
}

static inline size_t align256(size_t x) { return (x + 255) & ~(size_t)255; }

extern "C" void kernel_launch(void* const* d_in, const int* in_sizes, int n_in,
                              void* d_out, int out_size, void* d_ws, size_t ws_size,
                              hipStream_t stream) {
    const float* emb = (const float*)d_in[0];
    const int* iu = (const int*)d_in[1];
    const int* ib = (const int*)d_in[2];
    const int* it = (const int*)d_in[3];
    const float* uwi = (const float*)d_in[4];
    const float* ubi = (const float*)d_in[5];
    const float* uwo = (const float*)d_in[6];
    const float* ubo = (const float*)d_in[7];
    const float* bwi = (const float*)d_in[8];
    const float* bbi = (const float*)d_in[9];
    const float* bwo = (const float*)d_in[10];
    const float* bbo = (const float*)d_in[11];
    const float* twi = (const float*)d_in[12];
    const float* tbi = (const float*)d_in[13];
    const float* two_ = (const float*)d_in[14];
    const float* tbo = (const float*)d_in[15];
    const float* pwi = (const float*)d_in[16];
    const float* pbi = (const float*)d_in[17];
    const float* pwo = (const float*)d_in[18];
    const float* pbo = (const float*)d_in[19];

    const int nU = in_sizes[1];
    const int nB = in_sizes[2];
    const int nT = in_sizes[3];
    const int rowsU = nU;
    const int rowsB = nB / 2;
    const int rowsT = nT / 3;
    const long long NREF = (long long)nU + nB + nT;

    const size_t seg = (size_t)NOBJ * 64;
    const int gU = (rowsU + 63) / 64;
    const int gB = (rowsB + 63) / 64;
    const int gT = (rowsT + 31) / 32;
    const int nblkScan = (NOBJ + 255) / 256;

    conv_weights<<<(WTOT + 255) / 256, 256, 0, stream>>>(uwi, uwo, bwi, bwo, twi, two_, pwi, pwo);

    // ---- CSR workspace layout ----
    char* p = (char*)d_ws;
    u16* msgs = (u16*)p;      p += align256(2 * ((size_t)NREF * 64 + 16384));
    u32* counts = (u32*)p;    p += align256(4 * (size_t)NOBJ);
    u32* offs = (u32*)p;      p += align256(4 * (size_t)NOBJ);
    u32* cursor = (u32*)p;    p += align256(4 * (size_t)NOBJ);
    u32* bsum = (u32*)p;      p += align256(4 * 512);
    u32* reflist = (u32*)p;   p += align256(4 * (size_t)NREF);
    const size_t need = (size_t)(p - (char*)d_ws);

    if (ws_size >= need) {
        // ================= CSR path: zero fp atomics =================
        hipMemsetAsync(counts, 0, 4 * (size_t)NOBJ, stream);
        hipMemsetAsync(cursor, 0, 4 * (size_t)NOBJ, stream);

        int gRef = (int)((NREF + 255) / 256);
        hist_kernel<<<gRef, 256, 0, stream>>>(iu, nU, ib, nB, it, nT, counts);
        scan1_kernel<<<nblkScan, 256, 0, stream>>>(counts, offs, bsum);
        scan2_kernel<<<1, 512, 0, stream>>>(bsum, nblkScan);
        scan3_kernel<<<nblkScan, 256, 0, stream>>>(offs, bsum);
        fill_kernel<<<gRef, 256, 0, stream>>>(iu, nU, ib, nB, it, nT, offs, cursor, reflist);

        rel_pass_mfma<64, 4, 3, OFF_UWI, OFF_UWO><<<gU, 256, 0, stream>>>(
            emb, iu, rowsU, ubi, ubo, nullptr, nullptr, nullptr, nullptr, msgs, 0LL);
        rel_pass_mfma<128, 4, 3, OFF_BWI, OFF_BWO><<<gB, 256, 0, stream>>>(
            emb, ib, rowsB, bbi, bbo, nullptr, nullptr, nullptr, nullptr, msgs, (long long)nU * 64);
        rel_pass_mfma<192, 2, 3, OFF_TWI, OFF_TWO><<<gT, 128, 0, stream>>>(
            emb, it, rowsT, tbi, tbo, nullptr, nullptr, nullptr, nullptr, msgs, (long long)(nU + nB) * 64);

        agg_update<<<(NOBJ + 63) / 64, 256, 0, stream>>>(
            emb, msgs, offs, counts, reflist, pbi, pbo, (float*)d_out);
    } else if (ws_size >= seg * sizeof(double)) {
        // ================= round-4 f64 single-pass fallback =================
        double* ssum64 = (double*)d_ws;
        hipMemsetAsync(ssum64, 0, seg * sizeof(double), stream);
        rel_pass_mfma<64, 4, 2, OFF_UWI, OFF_UWO><<<gU, 256, 0, stream>>>(
            emb, iu, rowsU, ubi, ubo, nullptr, nullptr, nullptr, ssum64, nullptr, 0);
        rel_pass_mfma<128, 4, 2, OFF_BWI, OFF_BWO><<<gB, 256, 0, stream>>>(
            emb, ib, rowsB, bbi, bbo, nullptr, nullptr, nullptr, ssum64, nullptr, 0);
        rel_pass_mfma<192, 2, 2, OFF_TWI, OFF_TWO><<<gT, 128, 0, stream>>>(
            emb, it, rowsT, tbi, tbo, nullptr, nullptr, nullptr, ssum64, nullptr, 0);
        update_mfma<1><<<(NOBJ + 63) / 64, 256, 0, stream>>>(
            emb, nullptr, nullptr, ssum64, pbi, pbo, (float*)d_out);
    } else {
        // ================= two-pass f32 fallback =================
        float* mxf;
        float* ssum;
        if (ws_size >= 2 * seg * sizeof(float)) { mxf = (float*)d_ws; ssum = (float*)d_ws + seg; }
        else { mxf = (float*)d_out; ssum = (float*)d_ws; }
        hipMemsetAsync(mxf, 0, seg * sizeof(float), stream);
        hipMemsetAsync(ssum, 0, seg * sizeof(float), stream);
        rel_pass_mfma<64, 4, 0, OFF_UWI, OFF_UWO><<<gU, 256, 0, stream>>>(
            emb, iu, rowsU, ubi, ubo, (u32*)mxf, nullptr, nullptr, nullptr, nullptr, 0);
        rel_pass_mfma<128, 4, 0, OFF_BWI, OFF_BWO><<<gB, 256, 0, stream>>>(
            emb, ib, rowsB, bbi, bbo, (u32*)mxf, nullptr, nullptr, nullptr, nullptr, 0);
        rel_pass_mfma<192, 2, 0, OFF_TWI, OFF_TWO><<<gT, 128, 0, stream>>>(
            emb, it, rowsT, tbi, tbo, (u32*)mxf, nullptr, nullptr, nullptr, nullptr, 0);
        mx_decode_kernel<<<(int)((seg + 255) / 256), 256, 0, stream>>>((u32*)mxf, (long long)seg);
        rel_pass_mfma<64, 4, 1, OFF_UWI, OFF_UWO><<<gU, 256, 0, stream>>>(
            emb, iu, rowsU, ubi, ubo, nullptr, mxf, ssum, nullptr, nullptr, 0);
        rel_pass_mfma<128, 4, 1, OFF_BWI, OFF_BWO><<<gB, 256, 0, stream>>>(
            emb, ib, rowsB, bbi, bbo, nullptr, mxf, ssum, nullptr, nullptr, 0);
        rel_pass_mfma<192, 2, 1, OFF_TWI, OFF_TWO><<<gT, 128, 0, stream>>>(
            emb, it, rowsT, tbi, tbo, nullptr, mxf, ssum, nullptr, nullptr, 0);
        update_mfma<0><<<(NOBJ + 63) / 64, 256, 0, stream>>>(
            emb, mxf, ssum, nullptr, pbi, pbo, (float*)d_out);
    }
}

// Round 6
// 579.260 us; speedup vs baseline: 1.1944x; 1.1944x over previous
//
#include <hip/hip_runtime.h>
#include <hip/hip_bf16.h>
#include <math.h>

#define NOBJ 100000
#define SMOOTH 12.0f

typedef __attribute__((ext_vector_type(8))) short bf16x8;
typedef __attribute__((ext_vector_type(4))) float f32x4;
typedef unsigned short u16;
typedef unsigned int u32;
typedef unsigned long long u64;

// bf16 weight table
#define OFF_UWI 0
#define OFF_UWO 4096
#define OFF_BWI 8192
#define OFF_BWO 24576
#define OFF_TWI 40960
#define OFF_TWO 77824
#define OFF_PWI 114688
#define OFF_PWO 131072
#define WTOT    139264
__device__ u16 g_wbf[WTOT];

__device__ __forceinline__ u16 f2b(float x) {
    union { float f; u32 u; } v; v.f = x;
    u32 r = v.u + 0x7FFFu + ((v.u >> 16) & 1);
    return (u16)(r >> 16);
}
__device__ __forceinline__ float b2f(u16 b) {
    union { u32 u; float f; } v; v.u = ((u32)b) << 16; return v.f;
}
__device__ __forceinline__ u32 enc_f32(float v) {
    int b = __float_as_int(v);
    return (b >= 0) ? ((u32)b | 0x80000000u) : ~((u32)b);
}
__device__ __forceinline__ float mish_fast(float x) {
    float e = __expf(fminf(x, 15.f));
    float t = __builtin_fmaf(e, e, 2.f * e);
    return x * t * __builtin_amdgcn_rcpf(t + 2.f);
}
__device__ __forceinline__ double exp12_f64(float m) {
    float t = m * (SMOOTH * 1.4426950408889634f);
    float n = floorf(t);
    float f = exp2f(t - n);
    return ldexp((double)f, (int)n);
}
__device__ __forceinline__ float lse_from_sum(double S) {
    if (S == 0.0) return -3.0701134573253942f;  // log(1e-16)/12
    union { double d; u64 u; } vu; vu.d = S;
    int k = (int)((vu.u >> 52) & 0x7FF) - 1022;
    vu.u = (vu.u & 0x000FFFFFFFFFFFFFULL) | 0x3FE0000000000000ULL;
    float fr = (float)vu.d;
    return ((float)k + __log2f(fr)) * 0.057762265046662105f;  // *ln2/12
}

__global__ void conv_weights(const float* __restrict__ uwi, const float* __restrict__ uwo,
                             const float* __restrict__ bwi, const float* __restrict__ bwo,
                             const float* __restrict__ twi, const float* __restrict__ two_,
                             const float* __restrict__ pwi, const float* __restrict__ pwo) {
    int i = blockIdx.x * 256 + threadIdx.x;
    if (i >= WTOT) return;
    const float* src; int off;
    if      (i < OFF_UWO) { src = uwi; off = OFF_UWI; }
    else if (i < OFF_BWI) { src = uwo; off = OFF_UWO; }
    else if (i < OFF_BWO) { src = bwi; off = OFF_BWI; }
    else if (i < OFF_TWI) { src = bwo; off = OFF_BWO; }
    else if (i < OFF_TWO) { src = twi; off = OFF_TWI; }
    else if (i < OFF_PWI) { src = two_; off = OFF_TWO; }
    else if (i < OFF_PWO) { src = pwi; off = OFF_PWI; }
    else                  { src = pwo; off = OFF_PWO; }
    g_wbf[i] = f2b(src[i - off]);
}

__device__ __forceinline__ int lookup_obj(long long m,
                                          const int* __restrict__ iu, int nU,
                                          const int* __restrict__ ib, int nB,
                                          const int* __restrict__ it) {
    if (m < nU) return iu[m];
    m -= nU;
    if (m < nB) return ib[m];
    return it[m - nB];
}

// ---------- CSR build ----------
__global__ void hist_kernel(const int* __restrict__ iu, int nU,
                            const int* __restrict__ ib, int nB,
                            const int* __restrict__ it, int nT,
                            u32* __restrict__ counts) {
    long long t = (long long)blockIdx.x * 256 + threadIdx.x;
    if (t >= (long long)nU + nB + nT) return;
    atomicAdd(&counts[lookup_obj(t, iu, nU, ib, nB, it)], 1u);
}

__global__ void scan1_kernel(const u32* __restrict__ counts, u32* __restrict__ offs,
                             u32* __restrict__ bsum) {
    __shared__ u32 s[256];
    int t = threadIdx.x;
    int g = blockIdx.x * 256 + t;
    u32 v = (g < NOBJ) ? counts[g] : 0u;
    s[t] = v; __syncthreads();
    for (int off = 1; off < 256; off <<= 1) {
        u32 x = (t >= off) ? s[t - off] : 0u; __syncthreads();
        s[t] += x; __syncthreads();
    }
    if (g < NOBJ) offs[g] = s[t] - v;          // exclusive
    if (t == 255) bsum[blockIdx.x] = s[255];
}

__global__ void scan2_kernel(u32* __restrict__ bsum, int nblk) {
    __shared__ u32 s[512];
    int t = threadIdx.x;
    u32 v = (t < nblk) ? bsum[t] : 0u;
    s[t] = v; __syncthreads();
    for (int off = 1; off < 512; off <<= 1) {
        u32 x = (t >= off) ? s[t - off] : 0u; __syncthreads();
        s[t] += x; __syncthreads();
    }
    if (t < nblk) bsum[t] = s[t] - v;          // exclusive
}

__global__ void scan3_kernel(u32* __restrict__ offs, const u32* __restrict__ bsum) {
    int g = blockIdx.x * 256 + threadIdx.x;
    if (g < NOBJ) offs[g] += bsum[blockIdx.x];
}

// ref -> destination slot (so msg writes land pre-sorted by object)
__global__ void slot_kernel(const int* __restrict__ iu, int nU,
                            const int* __restrict__ ib, int nB,
                            const int* __restrict__ it, int nT,
                            const u32* __restrict__ offs, u32* __restrict__ cursor,
                            u32* __restrict__ slotByRef) {
    long long t = (long long)blockIdx.x * 256 + threadIdx.x;
    if (t >= (long long)nU + nB + nT) return;
    int obj = lookup_obj(t, iu, nU, ib, nB, it);
    u32 pos = atomicAdd(&cursor[obj], 1u);
    slotByRef[t] = offs[obj] + pos;
}

// ---------- fused relation MLP ----------
// MODE 0: atomicMax(enc) | MODE 1: f32 expsum atomic | MODE 2: f64 expsum atomic
// MODE 3: write f16 message rows directly to CSR slots (no atomics, sorted output)
template<int D, int MW, int MODE, int WOFF_I, int WOFF_O>
__global__ __launch_bounds__(64 * MW)
void rel_pass_mfma(const float* __restrict__ emb,
                   const int* __restrict__ idx, int nRows,
                   const float* __restrict__ bi, const float* __restrict__ bo,
                   u32* __restrict__ mx_enc, const float* __restrict__ mx,
                   float* __restrict__ ssum, double* __restrict__ ssum64,
                   u16* __restrict__ msgs_out, const u32* __restrict__ slotByRef,
                   long long baseRef) {
    constexpr int ARITY = D / 64;
    constexpr int NT = D / 16;
    constexpr int KT = D / 32;
    constexpr int M = MW * 16;
    __shared__ u16 xs[M * D];
    __shared__ u16 hs[M * D];
    __shared__ int objsm[M * ARITY];
    __shared__ u32 slotm[M * ARITY];

    const int tid = threadIdx.x;
    const int w = tid >> 6, l = tid & 63;
    const int lo = l & 15, hi = l >> 4;
    const int row0 = blockIdx.x * M;

    for (int i = tid; i < M * ARITY; i += 64 * MW) {
        int row = row0 + i / ARITY;
        bool ok = (row < nRows);
        objsm[i] = ok ? idx[(size_t)row * ARITY + i % ARITY] : -1;
        if (MODE == 3)
            slotm[i] = ok ? slotByRef[baseRef + (long long)row0 * ARITY + i] : 0xFFFFFFFFu;
    }
    __syncthreads();
    for (int i = tid; i < M * D / 4; i += 64 * MW) {
        int r = i / (D / 4), c4 = i % (D / 4);
        int obj = objsm[r * ARITY + (c4 >> 4)];
        float4 v = make_float4(0.f, 0.f, 0.f, 0.f);
        if (obj >= 0) v = *(const float4*)(emb + (size_t)obj * 64 + (c4 & 15) * 4);
        int sw = (r * D + c4 * 4) ^ ((r & 7) << 3);
        ushort4 o;
        o.x = f2b(v.x); o.y = f2b(v.y); o.z = f2b(v.z); o.w = f2b(v.w);
        *(ushort4*)&xs[sw] = o;
    }
    __syncthreads();

    f32x4 acc[NT];
    const int arow = w * 16 + lo;
    const int asw = ((arow & 7) << 3);

#pragma unroll
    for (int n = 0; n < NT; ++n) { float b = bi[n * 16 + lo]; acc[n] = (f32x4){b, b, b, b}; }
#pragma unroll
    for (int kk = 0; kk < KT; ++kk) {
        bf16x8 a = *(const bf16x8*)&xs[(arow * D + kk * 32 + hi * 8) ^ asw];
#pragma unroll
        for (int n = 0; n < NT; ++n) {
            bf16x8 b = *(const bf16x8*)&g_wbf[WOFF_I + (n * 16 + lo) * D + kk * 32 + hi * 8];
            acc[n] = __builtin_amdgcn_mfma_f32_16x16x32_bf16(a, b, acc[n], 0, 0, 0);
        }
    }
#pragma unroll
    for (int n = 0; n < NT; ++n) {
#pragma unroll
        for (int r = 0; r < 4; ++r) {
            int row = w * 16 + hi * 4 + r;
            int col = n * 16 + lo;
            hs[(row * D + col) ^ ((row & 7) << 3)] = f2b(mish_fast(acc[n][r]));
        }
    }
    __syncthreads();

#pragma unroll
    for (int n = 0; n < NT; ++n) { float b = bo[n * 16 + lo]; acc[n] = (f32x4){b, b, b, b}; }
#pragma unroll
    for (int kk = 0; kk < KT; ++kk) {
        bf16x8 a = *(const bf16x8*)&hs[(arow * D + kk * 32 + hi * 8) ^ asw];
#pragma unroll
        for (int n = 0; n < NT; ++n) {
            bf16x8 b = *(const bf16x8*)&g_wbf[WOFF_O + (n * 16 + lo) * D + kk * 32 + hi * 8];
            acc[n] = __builtin_amdgcn_mfma_f32_16x16x32_bf16(a, b, acc[n], 0, 0, 0);
        }
    }

    if (MODE == 3) {
        // msg -> f16 into hs, then slot-directed 16B-chunk dump (row = 128B contiguous)
#pragma unroll
        for (int n = 0; n < NT; ++n) {
            int col = n * 16 + lo;
#pragma unroll
            for (int r = 0; r < 4; ++r) {
                int row = w * 16 + hi * 4 + r;
                float m = b2f(xs[(row * D + col) ^ ((row & 7) << 3)]) + acc[n][r];
                _Float16 hv = (_Float16)m;
                hs[(row * D + col) ^ ((row & 7) << 3)] = *(u16*)&hv;
            }
        }
        __syncthreads();
        for (int i = tid; i < M * D / 8; i += 64 * MW) {
            int u = i * 8;
            int row = u / D, off = u - row * D;
            u32 slot = slotm[row * ARITY + (off >> 6)];
            if (slot == 0xFFFFFFFFu) continue;
            int sw2 = (row * D + off) ^ ((row & 7) << 3);
            *(bf16x8*)(msgs_out + (size_t)slot * 64 + (off & 63)) = *(const bf16x8*)&hs[sw2];
        }
    } else {
#pragma unroll
        for (int n = 0; n < NT; ++n) {
            int col = n * 16 + lo;
#pragma unroll
            for (int r = 0; r < 4; ++r) {
                int row = w * 16 + hi * 4 + r;
                int obj = objsm[row * ARITY + (col >> 6)];
                if (obj < 0) continue;
                float xv = b2f(xs[(row * D + col) ^ ((row & 7) << 3)]);
                float m = xv + acc[n][r];
                size_t dst = (size_t)obj * 64 + (col & 63);
                if (MODE == 0) atomicMax(&mx_enc[dst], enc_f32(m));
                else if (MODE == 1) atomicAdd(&ssum[dst], __expf(SMOOTH * (m - mx[dst])));
                else unsafeAtomicAdd(&ssum64[dst], exp12_f64(m));
            }
        }
    }
}

__global__ void mx_decode_kernel(u32* __restrict__ mx, long long n) {
    long long tid = (long long)blockIdx.x * blockDim.x + threadIdx.x;
    if (tid >= n) return;
    u32 u = mx[tid];
    float v;
    if (u == 0u) v = 0.0f;
    else {
        int b = (u & 0x80000000u) ? (int)(u & 0x7FFFFFFFu) : (int)(~u);
        v = __int_as_float(b);
    }
    ((float*)mx)[tid] = v;
}

// ---------- fused aggregate (contiguous stream) + update MLP ----------
__global__ __launch_bounds__(256)
void agg_update(const float* __restrict__ emb, const u16* __restrict__ msgs,
                const u32* __restrict__ offs, const u32* __restrict__ counts,
                const float* __restrict__ bi, const float* __restrict__ bo,
                float* __restrict__ out) {
    __shared__ u16 uin[64 * 128];
    __shared__ u16 h[64 * 128];
    const int tid = threadIdx.x;
    const int w = tid >> 6, l = tid & 63, lo = l & 15, hi = l >> 4;
    const int row0 = blockIdx.x * 64;

    // wave w aggregates objects row0 + w*16 .. +15; lane l = column; rows contiguous in msgs
    for (int rr = 0; rr < 16; ++rr) {
        int row = w * 16 + rr;
        int obj = row0 + row;
        float lse = -3.0701134573253942f, ev = 0.f;
        if (obj < NOBJ) {
            u32 off = offs[obj], n = counts[obj];
            const u16* mrow = msgs + (size_t)off * 64 + l;
            double S0 = 0.0, S1 = 0.0;
            u32 j = 0;
            for (; j + 4 <= n; j += 4) {
                float v0 = (float)(*(const _Float16*)(mrow + (size_t)(j + 0) * 64));
                float v1 = (float)(*(const _Float16*)(mrow + (size_t)(j + 1) * 64));
                float v2 = (float)(*(const _Float16*)(mrow + (size_t)(j + 2) * 64));
                float v3 = (float)(*(const _Float16*)(mrow + (size_t)(j + 3) * 64));
                S0 += exp12_f64(v0); S1 += exp12_f64(v1);
                S0 += exp12_f64(v2); S1 += exp12_f64(v3);
            }
            for (; j < n; ++j)
                S0 += exp12_f64((float)(*(const _Float16*)(mrow + (size_t)j * 64)));
            lse = lse_from_sum(S0 + S1);
            ev = emb[(size_t)obj * 64 + l];
        }
        uin[(row * 128 + l) ^ ((row & 7) << 3)] = f2b(lse);
        uin[(row * 128 + 64 + l) ^ ((row & 7) << 3)] = f2b(ev);
    }
    __syncthreads();

    const int arow = w * 16 + lo;
    const int asw = ((arow & 7) << 3);
    f32x4 acc[8];
#pragma unroll
    for (int n = 0; n < 8; ++n) { float b = bi[n * 16 + lo]; acc[n] = (f32x4){b, b, b, b}; }
#pragma unroll
    for (int kk = 0; kk < 4; ++kk) {
        bf16x8 a = *(const bf16x8*)&uin[(arow * 128 + kk * 32 + hi * 8) ^ asw];
#pragma unroll
        for (int n = 0; n < 8; ++n) {
            bf16x8 b = *(const bf16x8*)&g_wbf[OFF_PWI + (n * 16 + lo) * 128 + kk * 32 + hi * 8];
            acc[n] = __builtin_amdgcn_mfma_f32_16x16x32_bf16(a, b, acc[n], 0, 0, 0);
        }
    }
#pragma unroll
    for (int n = 0; n < 8; ++n) {
#pragma unroll
        for (int r = 0; r < 4; ++r) {
            int row = w * 16 + hi * 4 + r;
            int col = n * 16 + lo;
            h[(row * 128 + col) ^ ((row & 7) << 3)] = f2b(mish_fast(acc[n][r]));
        }
    }
    __syncthreads();

    f32x4 acc2[4];
#pragma unroll
    for (int n = 0; n < 4; ++n) { float b = bo[n * 16 + lo]; acc2[n] = (f32x4){b, b, b, b}; }
#pragma unroll
    for (int kk = 0; kk < 4; ++kk) {
        bf16x8 a = *(const bf16x8*)&h[(arow * 128 + kk * 32 + hi * 8) ^ asw];
#pragma unroll
        for (int n = 0; n < 4; ++n) {
            bf16x8 b = *(const bf16x8*)&g_wbf[OFF_PWO + (n * 16 + lo) * 128 + kk * 32 + hi * 8];
            acc2[n] = __builtin_amdgcn_mfma_f32_16x16x32_bf16(a, b, acc2[n], 0, 0, 0);
        }
    }
#pragma unroll
    for (int n = 0; n < 4; ++n) {
        int col = n * 16 + lo;
#pragma unroll
        for (int r = 0; r < 4; ++r) {
            int row = w * 16 + hi * 4 + r;
            int obj = row0 + row;
            if (obj < NOBJ)
                out[(size_t)obj * 64 + col] = emb[(size_t)obj * 64 + col] + acc2[n][r];
        }
    }
}

// update kernel for fallback paths
template<int P64>
__global__ __launch_bounds__(256)
void update_mfma(const float* __restrict__ emb,
                 const float* __restrict__ mx, const float* __restrict__ ssum,
                 const double* __restrict__ ssum64,
                 const float* __restrict__ bi, const float* __restrict__ bo,
                 float* __restrict__ out) {
    __shared__ u16 uin[64 * 128];
    __shared__ u16 h[64 * 128];
    const int tid = threadIdx.x;
    const int w = tid >> 6, l = tid & 63, lo = l & 15, hi = l >> 4;
    const int row0 = blockIdx.x * 64;

    for (int i = tid; i < 64 * 128; i += 256) {
        int r = i >> 7, c = i & 127;
        int obj = row0 + r;
        float v = 0.f;
        if (obj < NOBJ) {
            if (c < 64) {
                if (P64) v = lse_from_sum(ssum64[(size_t)obj * 64 + c]);
                else {
                    float s = ssum[(size_t)obj * 64 + c] + 1e-16f;
                    v = __logf(s) * (1.f / SMOOTH) + mx[(size_t)obj * 64 + c];
                }
            } else v = emb[(size_t)obj * 64 + (c - 64)];
        }
        uin[i ^ ((r & 7) << 3)] = f2b(v);
    }
    __syncthreads();

    const int arow = w * 16 + lo;
    const int asw = ((arow & 7) << 3);
    f32x4 acc[8];
#pragma unroll
    for (int n = 0; n < 8; ++n) { float b = bi[n * 16 + lo]; acc[n] = (f32x4){b, b, b, b}; }
#pragma unroll
    for (int kk = 0; kk < 4; ++kk) {
        bf16x8 a = *(const bf16x8*)&uin[(arow * 128 + kk * 32 + hi * 8) ^ asw];
#pragma unroll
        for (int n = 0; n < 8; ++n) {
            bf16x8 b = *(const bf16x8*)&g_wbf[OFF_PWI + (n * 16 + lo) * 128 + kk * 32 + hi * 8];
            acc[n] = __builtin_amdgcn_mfma_f32_16x16x32_bf16(a, b, acc[n], 0, 0, 0);
        }
    }
#pragma unroll
    for (int n = 0; n < 8; ++n) {
#pragma unroll
        for (int r = 0; r < 4; ++r) {
            int row = w * 16 + hi * 4 + r;
            int col = n * 16 + lo;
            h[(row * 128 + col) ^ ((row & 7) << 3)] = f2b(mish_fast(acc[n][r]));
        }
    }
    __syncthreads();
    f32x4 acc2[4];
#pragma unroll
    for (int n = 0; n < 4; ++n) { float b = bo[n * 16 + lo]; acc2[n] = (f32x4){b, b, b, b}; }
#pragma unroll
    for (int kk = 0; kk < 4; ++kk) {
        bf16x8 a = *(const bf16x8*)&h[(arow * 128 + kk * 32 + hi * 8) ^ asw];
#pragma unroll
        for (int n = 0; n < 4; ++n) {
            bf16x8 b = *(const bf16x8*)&g_wbf[OFF_PWO + (n * 16 + lo) * 128 + kk * 32 + hi * 8];
            acc2[n] = __builtin_amdgcn_mfma_f32_16x16x32_bf16(a, b, acc2[n], 0, 0, 0);
        }
    }
#pragma unroll
    for (int n = 0; n < 4; ++n) {
        int col = n * 16 + lo;
#pragma unroll
        for (int r = 0; r < 4; ++r) {
            int row = w * 16 + hi * 4 + r;
            int obj = row0 + row;
            if (obj < NOBJ)
                out[(size_t)obj * 64 + col] = emb[(size_t)obj * 64 + col] + acc2[n][r];
        }
    }
}

static inline size_t align256(size_t x) { return (x + 255) & ~(size_t)255; }

extern "C" void kernel_launch(void* const* d_in, const int* in_sizes, int n_in,
                              void* d_out, int out_size, void* d_ws, size_t ws_size,
                              hipStream_t stream) {
    const float* emb = (const float*)d_in[0];
    const int* iu = (const int*)d_in[1];
    const int* ib = (const int*)d_in[2];
    const int* it = (const int*)d_in[3];
    const float* uwi = (const float*)d_in[4];
    const float* ubi = (const float*)d_in[5];
    const float* uwo = (const float*)d_in[6];
    const float* ubo = (const float*)d_in[7];
    const float* bwi = (const float*)d_in[8];
    const float* bbi = (const float*)d_in[9];
    const float* bwo = (const float*)d_in[10];
    const float* bbo = (const float*)d_in[11];
    const float* twi = (const float*)d_in[12];
    const float* tbi = (const float*)d_in[13];
    const float* two_ = (const float*)d_in[14];
    const float* tbo = (const float*)d_in[15];
    const float* pwi = (const float*)d_in[16];
    const float* pbi = (const float*)d_in[17];
    const float* pwo = (const float*)d_in[18];
    const float* pbo = (const float*)d_in[19];

    const int nU = in_sizes[1];
    const int nB = in_sizes[2];
    const int nT = in_sizes[3];
    const int rowsU = nU;
    const int rowsB = nB / 2;
    const int rowsT = nT / 3;
    const long long NREF = (long long)nU + nB + nT;

    const size_t seg = (size_t)NOBJ * 64;
    const int gU = (rowsU + 63) / 64;
    const int gB = (rowsB + 63) / 64;
    const int gT = (rowsT + 31) / 32;
    const int nblkScan = (NOBJ + 255) / 256;

    conv_weights<<<(WTOT + 255) / 256, 256, 0, stream>>>(uwi, uwo, bwi, bwo, twi, two_, pwi, pwo);

    // ---- CSR workspace layout ----
    char* p = (char*)d_ws;
    u16* msgs = (u16*)p;        p += align256(2 * (size_t)NREF * 64);
    u32* counts = (u32*)p;      p += align256(4 * (size_t)NOBJ);
    u32* offs = (u32*)p;        p += align256(4 * (size_t)NOBJ);
    u32* cursor = (u32*)p;      p += align256(4 * (size_t)NOBJ);
    u32* bsum = (u32*)p;        p += align256(4 * 512);
    u32* slotByRef = (u32*)p;   p += align256(4 * (size_t)NREF);
    const size_t need = (size_t)(p - (char*)d_ws);

    if (ws_size >= need) {
        // ================= CSR path: sorted message writes, streaming aggregate =================
        hipMemsetAsync(counts, 0, 4 * (size_t)NOBJ, stream);
        hipMemsetAsync(cursor, 0, 4 * (size_t)NOBJ, stream);

        int gRef = (int)((NREF + 255) / 256);
        hist_kernel<<<gRef, 256, 0, stream>>>(iu, nU, ib, nB, it, nT, counts);
        scan1_kernel<<<nblkScan, 256, 0, stream>>>(counts, offs, bsum);
        scan2_kernel<<<1, 512, 0, stream>>>(bsum, nblkScan);
        scan3_kernel<<<nblkScan, 256, 0, stream>>>(offs, bsum);
        slot_kernel<<<gRef, 256, 0, stream>>>(iu, nU, ib, nB, it, nT, offs, cursor, slotByRef);

        rel_pass_mfma<64, 4, 3, OFF_UWI, OFF_UWO><<<gU, 256, 0, stream>>>(
            emb, iu, rowsU, ubi, ubo, nullptr, nullptr, nullptr, nullptr, msgs, slotByRef, 0LL);
        rel_pass_mfma<128, 4, 3, OFF_BWI, OFF_BWO><<<gB, 256, 0, stream>>>(
            emb, ib, rowsB, bbi, bbo, nullptr, nullptr, nullptr, nullptr, msgs, slotByRef, (long long)nU);
        rel_pass_mfma<192, 2, 3, OFF_TWI, OFF_TWO><<<gT, 128, 0, stream>>>(
            emb, it, rowsT, tbi, tbo, nullptr, nullptr, nullptr, nullptr, msgs, slotByRef, (long long)(nU + nB));

        agg_update<<<(NOBJ + 63) / 64, 256, 0, stream>>>(
            emb, msgs, offs, counts, pbi, pbo, (float*)d_out);
    } else if (ws_size >= seg * sizeof(double)) {
        // ================= f64 single-pass fallback =================
        double* ssum64 = (double*)d_ws;
        hipMemsetAsync(ssum64, 0, seg * sizeof(double), stream);
        rel_pass_mfma<64, 4, 2, OFF_UWI, OFF_UWO><<<gU, 256, 0, stream>>>(
            emb, iu, rowsU, ubi, ubo, nullptr, nullptr, nullptr, ssum64, nullptr, nullptr, 0);
        rel_pass_mfma<128, 4, 2, OFF_BWI, OFF_BWO><<<gB, 256, 0, stream>>>(
            emb, ib, rowsB, bbi, bbo, nullptr, nullptr, nullptr, ssum64, nullptr, nullptr, 0);
        rel_pass_mfma<192, 2, 2, OFF_TWI, OFF_TWO><<<gT, 128, 0, stream>>>(
            emb, it, rowsT, tbi, tbo, nullptr, nullptr, nullptr, ssum64, nullptr, nullptr, 0);
        update_mfma<1><<<(NOBJ + 63) / 64, 256, 0, stream>>>(
            emb, nullptr, nullptr, ssum64, pbi, pbo, (float*)d_out);
    } else {
        // ================= two-pass f32 fallback =================
        float* mxf;
        float* ssum;
        if (ws_size >= 2 * seg * sizeof(float)) { mxf = (float*)d_ws; ssum = (float*)d_ws + seg; }
        else { mxf = (float*)d_out; ssum = (float*)d_ws; }
        hipMemsetAsync(mxf, 0, seg * sizeof(float), stream);
        hipMemsetAsync(ssum, 0, seg * sizeof(float), stream);
        rel_pass_mfma<64, 4, 0, OFF_UWI, OFF_UWO><<<gU, 256, 0, stream>>>(
            emb, iu, rowsU, ubi, ubo, (u32*)mxf, nullptr, nullptr, nullptr, nullptr, nullptr, 0);
        rel_pass_mfma<128, 4, 0, OFF_BWI, OFF_BWO><<<gB, 256, 0, stream>>>(
            emb, ib, rowsB, bbi, bbo, (u32*)mxf, nullptr, nullptr, nullptr, nullptr, nullptr, 0);
        rel_pass_mfma<192, 2, 0, OFF_TWI, OFF_TWO><<<gT, 128, 0, stream>>>(
            emb, it, rowsT, tbi, tbo, (u32*)mxf, nullptr, nullptr, nullptr, nullptr, nullptr, 0);
        mx_decode_kernel<<<(int)((seg + 255) / 256), 256, 0, stream>>>((u32*)mxf, (long long)seg);
        rel_pass_mfma<64, 4, 1, OFF_UWI, OFF_UWO><<<gU, 256, 0, stream>>>(
            emb, iu, rowsU, ubi, ubo, nullptr, mxf, ssum, nullptr, nullptr, nullptr, 0);
        rel_pass_mfma<128, 4, 1, OFF_BWI, OFF_BWO><<<gB, 256, 0, stream>>>(
            emb, ib, rowsB, bbi, bbo, nullptr, mxf, ssum, nullptr, nullptr, nullptr, 0);
        rel_pass_mfma<192, 2, 1, OFF_TWI, OFF_TWO><<<gT, 128, 0, stream>>>(
            emb, it, rowsT, tbi, tbo, nullptr, mxf, ssum, nullptr, nullptr, nullptr, 0);
        update_mfma<0><<<(NOBJ + 63) / 64, 256, 0, stream>>>(
            emb, mxf, ssum, nullptr, pbi, pbo, (float*)d_out);
    }
}